// Round 3
// baseline (3192.588 us; speedup 1.0000x reference)
//
#include <hip/hip_runtime.h>
#include <hip/hip_bf16.h>

// B=4096, L=100 (SEQLEN=99), d=256, K=2d=512.
// x[b,t,:] = [qa[b,t,:], q[b,t,:]]  (t=0..98)
// gate=sigmoid(x@Wg^T+bg), kq=tanh(x@Wk^T+bk), reset=sigmoid(x@Wr^T+br)
// h_0 = exp; h_{t+1} = r_t*h_t + (1-r_t)*(gate_t*kq_t); out[b] = [exp, h_1..h_99]
//
// Round-3 structure: 1 block / b, 512 threads (8 waves), wave w owns d-cols
// [w*32, w*32+32) (j=0,1 sub-tiles of 16).
//  - x staged as bf16 in LDS per k-QUARTER (99x128, 25344B), double-buffered
//    (50688B static LDS total), XOR-swizzled for conflict-free ds_read_b128.
//    Global loads for quarter q+1 are issued BEFORE GEMM(q) (T14 split).
//  - recurrence done fully in-register: each lane's 4 consecutive t-steps are
//    composed into one affine map (A,B); a 4-step shuffle scan over the lgrp
//    dimension + sequential carry over the 7 m-tiles replaces the LDS rg
//    buffer and the 99-step serial loop.

typedef __attribute__((ext_vector_type(4))) float f32x4;
typedef __attribute__((ext_vector_type(8))) short short8;

union BF8 { short8 s; unsigned short u[8]; };

static constexpr int QT_BYTES = 99 * 256;          // one k-quarter staged (bf16), 25344 B

__device__ __forceinline__ unsigned short f2bf(float f) {
  unsigned int u = __float_as_uint(f);
  return (unsigned short)((u + 0x7fffu + ((u >> 16) & 1u)) >> 16);   // RNE
}

__device__ __forceinline__ float sigm(float x) { return 1.f / (1.f + __expf(-x)); }
__device__ __forceinline__ float tanh_(float x) {
  x = fminf(fmaxf(x, -15.f), 15.f);
  float e = __expf(2.f * x);
  return (e - 1.f) / (e + 1.f);
}

// Pack Wg|Wk|Wr (each 256x512 f32, row-major) into bf16 B-fragment order:
// [nt(48)][ks(16)][lane(64)][j(8)]; value = W_sel[nt%16*16 + (l&15)][ks*32+(l>>4)*8+j]
__global__ void pack_w(const float* __restrict__ Wg, const float* __restrict__ Wk,
                       const float* __restrict__ Wr, unsigned short* __restrict__ out) {
  int idx = blockIdx.x * 256 + threadIdx.x;        // 0 .. 49151  (48*16*64)
  int l = idx & 63;
  int rest = idx >> 6;
  int ks = rest & 15;
  int nt = rest >> 4;                              // 0..47
  int sel = nt >> 4;
  const float* W = (sel == 0) ? Wg : ((sel == 1) ? Wk : Wr);
  int n = ((nt & 15) * 16) + (l & 15);             // 0..255
  const float* p = W + (size_t)n * 512 + ks * 32 + ((l >> 4) * 8);
  unsigned short* o = out + (size_t)idx * 8;
#pragma unroll
  for (int j = 0; j < 8; ++j) o[j] = f2bf(p[j]);
}

template <bool PACKED>
__device__ __forceinline__ short8 ldB(const unsigned short* __restrict__ wpk,
                                      const float* __restrict__ W,
                                      int nt_global, int ks, int l) {
  if constexpr (PACKED) {
    return *(const short8*)(wpk + (((size_t)nt_global * 16 + ks) * 64 + l) * 8);
  } else {
    int n = ((nt_global & 15) * 16) + (l & 15);
    const float* p = W + (size_t)n * 512 + ks * 32 + ((l >> 4) * 8);
    f32x4 v0 = *(const f32x4*)p;
    f32x4 v1 = *(const f32x4*)(p + 4);
    BF8 r;
#pragma unroll
    for (int j = 0; j < 4; ++j) { r.u[j] = f2bf(v0[j]); r.u[4 + j] = f2bf(v1[j]); }
    return r.s;
  }
}

template <bool PACKED>
__global__ __launch_bounds__(512, 2) void fused_kernel(
    const float* __restrict__ q, const float* __restrict__ qa,
    const float* __restrict__ expw,
    const float* __restrict__ Wg, const float* __restrict__ bg,
    const float* __restrict__ Wk, const float* __restrict__ bk,
    const float* __restrict__ Wr, const float* __restrict__ br,
    const unsigned short* __restrict__ wpk,
    float* __restrict__ out) {
  __shared__ char smem[2 * QT_BYTES];              // 50688 B static
  const int b = blockIdx.x;
  const int tid = threadIdx.x;
  const int w = tid >> 6;                          // wave 0..7
  const int l = tid & 63;
  const int lrow = l & 15;
  const int lgrp = l >> 4;

  const float* xqa = qa + (size_t)b * 25600;       // x[:, 0:256)
  const float* xq  = q  + (size_t)b * 25600;       // x[:, 256:512)

  // staging helpers: quarter qq covers k in [qq*128, qq*128+128)
  // 3168 chunks of f32x4 (16B src -> 8B bf16 dst): 6 full iters + 96-tail
  f32x4 pre[7];
#define ISSUE(qq)                                                            \
  {                                                                          \
    const float* src = ((qq) < 2 ? xqa : xq) + ((qq) & 1) * 128;             \
    _Pragma("unroll")                                                        \
    for (int it = 0; it < 7; ++it) {                                         \
      int cid = it * 512 + tid;                                              \
      if (cid < 3168) {                                                      \
        int row = cid >> 5, c = cid & 31;                                    \
        pre[it] = *(const f32x4*)(src + row * 256 + c * 4);                  \
      }                                                                      \
    }                                                                        \
  }
#define COMMIT(bufi)                                                         \
  {                                                                          \
    char* dst = smem + (bufi) * QT_BYTES;                                    \
    _Pragma("unroll")                                                        \
    for (int it = 0; it < 7; ++it) {                                         \
      int cid = it * 512 + tid;                                              \
      if (cid < 3168) {                                                      \
        int row = cid >> 5, c = cid & 31;                                    \
        unsigned int w0 = ((unsigned int)f2bf(pre[it][1]) << 16) | f2bf(pre[it][0]); \
        unsigned int w1 = ((unsigned int)f2bf(pre[it][3]) << 16) | f2bf(pre[it][2]); \
        int byte = row * 256 + ((c * 8) ^ ((row & 7) << 4));                 \
        *(unsigned long long*)(dst + byte) = ((unsigned long long)w1 << 32) | w0; \
      }                                                                      \
    }                                                                        \
  }

  ISSUE(0);
  COMMIT(0);
  __syncthreads();

  f32x4 accG[7][2], accK[7][2], accR[7][2];
#pragma unroll
  for (int mt = 0; mt < 7; ++mt)
#pragma unroll
    for (int j = 0; j < 2; ++j) {
      accG[mt][j] = (f32x4){0.f, 0.f, 0.f, 0.f};
      accK[mt][j] = (f32x4){0.f, 0.f, 0.f, 0.f};
      accR[mt][j] = (f32x4){0.f, 0.f, 0.f, 0.f};
    }

  int rowOff[7], swz[7];
#pragma unroll
  for (int mt = 0; mt < 7; ++mt) {
    int t = mt * 16 + lrow;
    t = (t > 98) ? 98 : t;                         // clamp padded rows (masked later)
    rowOff[mt] = t * 256;
    swz[mt] = (t & 7) << 4;
  }
  const int lgoff = lgrp * 16;

  for (int qq = 0; qq < 4; ++qq) {
    if (qq == 0) ISSUE(1);
    if (qq == 1) ISSUE(2);
    if (qq == 2) ISSUE(3);
    const char* base = smem + (qq & 1) * QT_BYTES;
#pragma unroll
    for (int kk = 0; kk < 4; ++kk) {
      const int ks = qq * 4 + kk;
      const int koff = kk * 64 + lgoff;
      BF8 aF[7];
#pragma unroll
      for (int mt = 0; mt < 7; ++mt)
        aF[mt].s = *(const short8*)(base + rowOff[mt] + (koff ^ swz[mt]));
#pragma unroll
      for (int j = 0; j < 2; ++j) {
        short8 bG = ldB<PACKED>(wpk, Wg, w * 2 + j, ks, l);
#pragma unroll
        for (int mt = 0; mt < 7; ++mt)
          accG[mt][j] = __builtin_amdgcn_mfma_f32_16x16x32_bf16(aF[mt].s, bG, accG[mt][j], 0, 0, 0);
        short8 bK = ldB<PACKED>(wpk, Wk, 16 + w * 2 + j, ks, l);
#pragma unroll
        for (int mt = 0; mt < 7; ++mt)
          accK[mt][j] = __builtin_amdgcn_mfma_f32_16x16x32_bf16(aF[mt].s, bK, accK[mt][j], 0, 0, 0);
        short8 bR = ldB<PACKED>(wpk, Wr, 32 + w * 2 + j, ks, l);
#pragma unroll
        for (int mt = 0; mt < 7; ++mt)
          accR[mt][j] = __builtin_amdgcn_mfma_f32_16x16x32_bf16(aF[mt].s, bR, accR[mt][j], 0, 0, 0);
      }
    }
    if (qq < 3) {
      __syncthreads();                             // all reads of target buffer done
      COMMIT((qq + 1) & 1);
      __syncthreads();                             // staged data visible
    }
  }

  // ---- epilogue: activations + in-register affine scan + direct stores ----
  // acc layout per (mt,j): lane (lrow,lgrp) holds t = mt*16 + lgrp*4 + r,
  // d = w*32 + j*16 + lrow. Step map: h' = rr*h + cc, cc = (1-rr)*gate*kq.
  float* ob = out + (size_t)b * 25600;
#pragma unroll
  for (int j = 0; j < 2; ++j) {
    const int d = w * 32 + j * 16 + lrow;
    const float bgv = bg[d], bkv = bk[d], brv = br[d];
    float h = expw[d];
    if (lgrp == 0) ob[d] = h;                      // out[b,0,:] = exp
#pragma unroll
    for (int mt = 0; mt < 7; ++mt) {
      float rr[4], cc[4];
#pragma unroll
      for (int r = 0; r < 4; ++r) {
        const int t = mt * 16 + lgrp * 4 + r;
        if (t < 99) {
          float rv = sigm(accR[mt][j][r] + brv);
          float gv = sigm(accG[mt][j][r] + bgv);
          float kv = tanh_(accK[mt][j][r] + bkv);
          rr[r] = rv;
          cc[r] = (1.f - rv) * (gv * kv);
        } else { rr[r] = 1.f; cc[r] = 0.f; }       // identity step for padding
      }
      // compose this lane's 4 steps: h -> A*h + B
      const float A  = ((rr[0] * rr[1]) * rr[2]) * rr[3];
      const float Bc = ((cc[0] * rr[1] + cc[1]) * rr[2] + cc[2]) * rr[3] + cc[3];
      // shuffle scan across the 4 lgrp groups (same lrow column)
      float hcur = h, hstart = h;
#pragma unroll
      for (int g = 0; g < 4; ++g) {
        float ag  = __shfl(A,  lrow + (g << 4), 64);
        float bg_ = __shfl(Bc, lrow + (g << 4), 64);
        hstart = (lgrp == g) ? hcur : hstart;      // exclusive prefix for own group
        hcur = __builtin_fmaf(ag, hcur, bg_);
      }
      h = hcur;                                    // carry to next m-tile
      // reconstruct the 4 per-step h values and store
      float hh = hstart;
#pragma unroll
      for (int r = 0; r < 4; ++r) {
        const int t = mt * 16 + lgrp * 4 + r;
        hh = __builtin_fmaf(rr[r], hh, cc[r]);
        if (t < 99) ob[(t + 1) * 256 + d] = hh;
      }
    }
  }
#undef ISSUE
#undef COMMIT
}

extern "C" void kernel_launch(void* const* d_in, const int* in_sizes, int n_in,
                              void* d_out, int out_size, void* d_ws, size_t ws_size,
                              hipStream_t stream) {
  const float* q    = (const float*)d_in[0];
  const float* qa   = (const float*)d_in[1];
  const float* expw = (const float*)d_in[2];
  const float* Wg   = (const float*)d_in[3];
  const float* bg   = (const float*)d_in[4];
  const float* Wk   = (const float*)d_in[5];
  const float* bk   = (const float*)d_in[6];
  const float* Wr   = (const float*)d_in[7];
  const float* br   = (const float*)d_in[8];
  float* out = (float*)d_out;

  const bool packed = ws_size >= (size_t)(48 * 16 * 64 * 8 * 2);

  if (packed) {
    unsigned short* wpk = (unsigned short*)d_ws;
    pack_w<<<192, 256, 0, stream>>>(Wg, Wk, Wr, wpk);
    fused_kernel<true><<<4096, 512, 0, stream>>>(q, qa, expw, Wg, bg, Wk, bk, Wr, br, wpk, out);
  } else {
    fused_kernel<false><<<4096, 512, 0, stream>>>(q, qa, expw, Wg, bg, Wk, bk, Wr, br, nullptr, out);
  }
}

// Round 4
// 1280.922 us; speedup vs baseline: 2.4924x; 2.4924x over previous
//
#include <hip/hip_runtime.h>
#include <hip/hip_bf16.h>

// B=4096, L=100 (SEQLEN=99), d=256, K=2d=512.
// x[b,t,:] = [qa[b,t,:], q[b,t,:]]  (t=0..98)
// gate=sigmoid(x@Wg^T+bg), kq=tanh(x@Wk^T+bk), reset=sigmoid(x@Wr^T+br)
// h_0 = exp; h_{t+1} = r_t*h_t + (1-r_t)*(gate_t*kq_t); out[b] = [exp, h_1..h_99]
//
// Round-4 structure: 1 block / b, 512 threads (8 waves), wave w owns d-cols
// [w*32, w*32+32) (j=0,1 sub-tiles of 16).
//  - x staged as bf16 per k-QUARTER (99x128 = 25344B), DOUBLE-buffered in LDS
//    (50688B), XOR-swizzled. STAGE(q+1) is commit-immediate (load -> cvt_pk ->
//    ds_write, no long-lived registers -- round 3's held-register prefetch
//    spilled to scratch: 12.5 GB of HBM spill traffic) and sits in the same
//    barrier region as GEMM(q) so its global loads + VALU hide under MFMA.
//  - f32->bf16 via __float22bfloat162_rn (v_cvt_pk_bf16_f32), ~3x fewer VALU
//    ops than a hand-rolled RNE.
//  - recurrence fully in-register: each lane composes its 4 consecutive
//    t-steps into one affine map; 4-step shuffle scan over lgrp + sequential
//    carry over the 7 m-tiles. No rg LDS buffer, no serial 99-step loop.

typedef __attribute__((ext_vector_type(4))) float f32x4;
typedef __attribute__((ext_vector_type(8))) short short8;

union BF8 { short8 s; unsigned short u[8]; };

static constexpr int QT_BYTES = 99 * 256;          // one staged k-quarter, 25344 B

__device__ __forceinline__ unsigned short f2bf(float f) {
  unsigned int u = __float_as_uint(f);
  return (unsigned short)((u + 0x7fffu + ((u >> 16) & 1u)) >> 16);   // RNE
}

__device__ __forceinline__ unsigned int pk2bf(float lo, float hi) {
  __hip_bfloat162 h = __float22bfloat162_rn(make_float2(lo, hi));    // v_cvt_pk_bf16_f32
  union { __hip_bfloat162 h2; unsigned int u; } cv;
  cv.h2 = h;
  return cv.u;
}

__device__ __forceinline__ float sigm(float x) { return 1.f / (1.f + __expf(-x)); }
__device__ __forceinline__ float tanh_(float x) {
  x = fminf(fmaxf(x, -15.f), 15.f);
  float e = __expf(2.f * x);
  return (e - 1.f) / (e + 1.f);
}

// Pack Wg|Wk|Wr (each 256x512 f32, row-major) into bf16 B-fragment order:
// [nt(48)][ks(16)][lane(64)][j(8)]; value = W_sel[nt%16*16 + (l&15)][ks*32+(l>>4)*8+j]
__global__ void pack_w(const float* __restrict__ Wg, const float* __restrict__ Wk,
                       const float* __restrict__ Wr, unsigned short* __restrict__ out) {
  int idx = blockIdx.x * 256 + threadIdx.x;        // 0 .. 49151  (48*16*64)
  int l = idx & 63;
  int rest = idx >> 6;
  int ks = rest & 15;
  int nt = rest >> 4;                              // 0..47
  int sel = nt >> 4;
  const float* W = (sel == 0) ? Wg : ((sel == 1) ? Wk : Wr);
  int n = ((nt & 15) * 16) + (l & 15);             // 0..255
  const float* p = W + (size_t)n * 512 + ks * 32 + ((l >> 4) * 8);
  unsigned short* o = out + (size_t)idx * 8;
#pragma unroll
  for (int j = 0; j < 8; ++j) o[j] = f2bf(p[j]);
}

template <bool PACKED>
__device__ __forceinline__ short8 ldB(const unsigned short* __restrict__ wpk,
                                      const float* __restrict__ W,
                                      int nt_global, int ks, int l) {
  if constexpr (PACKED) {
    return *(const short8*)(wpk + (((size_t)nt_global * 16 + ks) * 64 + l) * 8);
  } else {
    int n = ((nt_global & 15) * 16) + (l & 15);
    const float* p = W + (size_t)n * 512 + ks * 32 + ((l >> 4) * 8);
    f32x4 v0 = *(const f32x4*)p;
    f32x4 v1 = *(const f32x4*)(p + 4);
    BF8 r;
#pragma unroll
    for (int j = 0; j < 4; ++j) { r.u[j] = f2bf(v0[j]); r.u[4 + j] = f2bf(v1[j]); }
    return r.s;
  }
}

template <bool PACKED>
__global__ __launch_bounds__(512, 2) void fused_kernel(
    const float* __restrict__ q, const float* __restrict__ qa,
    const float* __restrict__ expw,
    const float* __restrict__ Wg, const float* __restrict__ bg,
    const float* __restrict__ Wk, const float* __restrict__ bk,
    const float* __restrict__ Wr, const float* __restrict__ br,
    const unsigned short* __restrict__ wpk,
    float* __restrict__ out) {
  __shared__ char smem[2 * QT_BYTES];              // 50688 B
  const int b = blockIdx.x;
  const int tid = threadIdx.x;
  const int w = tid >> 6;                          // wave 0..7
  const int l = tid & 63;
  const int lrow = l & 15;
  const int lgrp = l >> 4;

  const float* xqa = qa + (size_t)b * 25600;       // x[:, 0:256)
  const float* xq  = q  + (size_t)b * 25600;       // x[:, 256:512)

  // quarter qq covers k in [qq*128, qq*128+128): 99 rows x 32 f32x4 chunks.
  // commit-immediate: load -> cvt_pk -> ds_write, nothing held across phases.
#define STAGE(qq, bufi)                                                      \
  {                                                                          \
    const float* src = ((qq) < 2 ? xqa : xq) + ((qq) & 1) * 128;             \
    char* dst = smem + (bufi) * QT_BYTES;                                    \
    _Pragma("unroll")                                                        \
    for (int it = 0; it < 7; ++it) {                                         \
      int cid = it * 512 + tid;                                              \
      if (cid < 3168) {                                                      \
        int row = cid >> 5, c = cid & 31;                                    \
        f32x4 v = *(const f32x4*)(src + row * 256 + c * 4);                  \
        unsigned long long pkd =                                             \
            ((unsigned long long)pk2bf(v[2], v[3]) << 32) | pk2bf(v[0], v[1]); \
        int byte = row * 256 + ((c * 8) ^ ((row & 7) << 4));                 \
        *(unsigned long long*)(dst + byte) = pkd;                            \
      }                                                                      \
    }                                                                        \
  }

  STAGE(0, 0);
  __syncthreads();

  f32x4 accG[7][2], accK[7][2], accR[7][2];
#pragma unroll
  for (int mt = 0; mt < 7; ++mt)
#pragma unroll
    for (int j = 0; j < 2; ++j) {
      accG[mt][j] = (f32x4){0.f, 0.f, 0.f, 0.f};
      accK[mt][j] = (f32x4){0.f, 0.f, 0.f, 0.f};
      accR[mt][j] = (f32x4){0.f, 0.f, 0.f, 0.f};
    }

  int rowOff[7], swz[7];
#pragma unroll
  for (int mt = 0; mt < 7; ++mt) {
    int t = mt * 16 + lrow;
    t = (t > 98) ? 98 : t;                         // clamp padded rows (masked later)
    rowOff[mt] = t * 256;
    swz[mt] = (t & 7) << 4;
  }
  const int lgoff = lgrp * 16;

#pragma unroll
  for (int qq = 0; qq < 4; ++qq) {
    // stage next quarter into the OTHER buffer; overlaps with GEMM below
    // (separate LDS region; one barrier per quarter keeps it race-free)
    if (qq < 3) STAGE(qq + 1, (qq + 1) & 1);
    const char* base = smem + (qq & 1) * QT_BYTES;
#pragma unroll
    for (int kk = 0; kk < 4; ++kk) {
      const int ks = qq * 4 + kk;
      const int koff = kk * 64 + lgoff;
      BF8 aF[7];
#pragma unroll
      for (int mt = 0; mt < 7; ++mt)
        aF[mt].s = *(const short8*)(base + rowOff[mt] + (koff ^ swz[mt]));
#pragma unroll
      for (int j = 0; j < 2; ++j) {
        short8 bG = ldB<PACKED>(wpk, Wg, w * 2 + j, ks, l);
#pragma unroll
        for (int mt = 0; mt < 7; ++mt)
          accG[mt][j] = __builtin_amdgcn_mfma_f32_16x16x32_bf16(aF[mt].s, bG, accG[mt][j], 0, 0, 0);
        short8 bK = ldB<PACKED>(wpk, Wk, 16 + w * 2 + j, ks, l);
#pragma unroll
        for (int mt = 0; mt < 7; ++mt)
          accK[mt][j] = __builtin_amdgcn_mfma_f32_16x16x32_bf16(aF[mt].s, bK, accK[mt][j], 0, 0, 0);
        short8 bR = ldB<PACKED>(wpk, Wr, 32 + w * 2 + j, ks, l);
#pragma unroll
        for (int mt = 0; mt < 7; ++mt)
          accR[mt][j] = __builtin_amdgcn_mfma_f32_16x16x32_bf16(aF[mt].s, bR, accR[mt][j], 0, 0, 0);
      }
    }
    __syncthreads();                               // staged data visible; buffer reads done
  }

  // ---- epilogue: activations + in-register affine scan + direct stores ----
  // acc layout per (mt,j): lane (lrow,lgrp) holds t = mt*16 + lgrp*4 + r,
  // d = w*32 + j*16 + lrow. Step map: h' = rr*h + cc, cc = (1-rr)*gate*kq.
  float* ob = out + (size_t)b * 25600;
#pragma unroll
  for (int j = 0; j < 2; ++j) {
    const int d = w * 32 + j * 16 + lrow;
    const float bgv = bg[d], bkv = bk[d], brv = br[d];
    float h = expw[d];
    if (lgrp == 0) ob[d] = h;                      // out[b,0,:] = exp
#pragma unroll
    for (int mt = 0; mt < 7; ++mt) {
      float rr[4], cc[4];
#pragma unroll
      for (int r = 0; r < 4; ++r) {
        const int t = mt * 16 + lgrp * 4 + r;
        if (t < 99) {
          float rv = sigm(accR[mt][j][r] + brv);
          float gv = sigm(accG[mt][j][r] + bgv);
          float kv = tanh_(accK[mt][j][r] + bkv);
          rr[r] = rv;
          cc[r] = (1.f - rv) * (gv * kv);
        } else { rr[r] = 1.f; cc[r] = 0.f; }       // identity step for padding
      }
      // compose this lane's 4 steps: h -> A*h + B
      const float A  = ((rr[0] * rr[1]) * rr[2]) * rr[3];
      const float Bc = ((cc[0] * rr[1] + cc[1]) * rr[2] + cc[2]) * rr[3] + cc[3];
      // shuffle scan across the 4 lgrp groups (same lrow column)
      float hcur = h, hstart = h;
#pragma unroll
      for (int g = 0; g < 4; ++g) {
        float ag  = __shfl(A,  lrow + (g << 4), 64);
        float bg_ = __shfl(Bc, lrow + (g << 4), 64);
        hstart = (lgrp == g) ? hcur : hstart;      // exclusive prefix for own group
        hcur = __builtin_fmaf(ag, hcur, bg_);
      }
      h = hcur;                                    // carry to next m-tile
      // reconstruct the 4 per-step h values and store
      float hh = hstart;
#pragma unroll
      for (int r = 0; r < 4; ++r) {
        const int t = mt * 16 + lgrp * 4 + r;
        hh = __builtin_fmaf(rr[r], hh, cc[r]);
        if (t < 99) ob[(t + 1) * 256 + d] = hh;
      }
    }
  }
#undef STAGE
}

extern "C" void kernel_launch(void* const* d_in, const int* in_sizes, int n_in,
                              void* d_out, int out_size, void* d_ws, size_t ws_size,
                              hipStream_t stream) {
  const float* q    = (const float*)d_in[0];
  const float* qa   = (const float*)d_in[1];
  const float* expw = (const float*)d_in[2];
  const float* Wg   = (const float*)d_in[3];
  const float* bg   = (const float*)d_in[4];
  const float* Wk   = (const float*)d_in[5];
  const float* bk   = (const float*)d_in[6];
  const float* Wr   = (const float*)d_in[7];
  const float* br   = (const float*)d_in[8];
  float* out = (float*)d_out;

  const bool packed = ws_size >= (size_t)(48 * 16 * 64 * 8 * 2);

  if (packed) {
    unsigned short* wpk = (unsigned short*)d_ws;
    pack_w<<<192, 256, 0, stream>>>(Wg, Wk, Wr, wpk);
    fused_kernel<true><<<4096, 512, 0, stream>>>(q, qa, expw, Wg, bg, Wk, bk, Wr, br, wpk, out);
  } else {
    fused_kernel<false><<<4096, 512, 0, stream>>>(q, qa, expw, Wg, bg, Wk, bk, Wr, br, nullptr, out);
  }
}

// Round 5
// 1254.759 us; speedup vs baseline: 2.5444x; 1.0209x over previous
//
#include <hip/hip_runtime.h>
#include <hip/hip_bf16.h>

// B=4096, L=100 (SEQLEN=99), d=256, K=2d=512.
// x[b,t,:] = [qa[b,t,:], q[b,t,:]]  (t=0..98)
// gate=sigmoid(x@Wg^T+bg), kq=tanh(x@Wk^T+bk), reset=sigmoid(x@Wr^T+br)
// h_0 = exp; h_{t+1} = r_t*h_t + (1-r_t)*(gate_t*kq_t); out[b] = [exp, h_1..h_99]
//
// Round-5 structure: 1 block / b, 512 threads (8 waves), wave w owns d-cols
// [w*32, w*32+32) (j=0,1 sub-tiles of 16).
//  - x staged as RAW F32 via __builtin_amdgcn_global_load_lds (async DMA,
//    zero registers held, zero staging VALU -- rounds 3/4 spilled ~2 GB of
//    scratch because register staging coexisted with 168 live acc regs).
//    Double-buffered k-quarters: 2 x 100 rows x 512 B = 102400 B LDS.
//  - LDS layout permutation done by PRE-SWIZZLING THE GLOBAL SOURCE address
//    (DMA dest must be linear): row slot = (k16 + 9*row) & 31. Per
//    ds_read_b128 this gives <=2 lanes per 16B slot (collision requires
//    dlgrp=2, drow=4 exactly) -> near-conflict-free.
//  - f32->bf16 at fragment read: 2 x ds_read_b128 + 4 cvt_pk per fragment,
//    reused across 42 MFMAs (3 matrices x 2 n-tiles).
//  - recurrence fully in-register (affine-map compose + shuffle scan).
//  - __launch_bounds__(512,1): occupancy is LDS-capped at 1 block/CU anyway;
//    give the allocator the full register file so nothing can spill.

typedef __attribute__((ext_vector_type(4))) float f32x4;
typedef __attribute__((ext_vector_type(8))) short short8;

union BF8 { short8 s; unsigned short u[8]; unsigned int w4[4]; };

static constexpr int QROWS    = 100;             // 99 used + 1 pad row
static constexpr int QT_BYTES = QROWS * 512;     // one f32 k-quarter, 51200 B

__device__ __forceinline__ unsigned short f2bf(float f) {
  unsigned int u = __float_as_uint(f);
  return (unsigned short)((u + 0x7fffu + ((u >> 16) & 1u)) >> 16);   // RNE
}

__device__ __forceinline__ unsigned int pk2bf(float lo, float hi) {
  __hip_bfloat162 h = __float22bfloat162_rn(make_float2(lo, hi));    // v_cvt_pk_bf16_f32
  union { __hip_bfloat162 h2; unsigned int u; } cv;
  cv.h2 = h;
  return cv.u;
}

__device__ __forceinline__ float sigm(float x) { return 1.f / (1.f + __expf(-x)); }
__device__ __forceinline__ float tanh_(float x) {
  x = fminf(fmaxf(x, -15.f), 15.f);
  float e = __expf(2.f * x);
  return (e - 1.f) / (e + 1.f);
}

// Pack Wg|Wk|Wr (each 256x512 f32, row-major) into bf16 B-fragment order:
// [nt(48)][ks(16)][lane(64)][j(8)]; value = W_sel[nt%16*16 + (l&15)][ks*32+(l>>4)*8+j]
__global__ void pack_w(const float* __restrict__ Wg, const float* __restrict__ Wk,
                       const float* __restrict__ Wr, unsigned short* __restrict__ out) {
  int idx = blockIdx.x * 256 + threadIdx.x;        // 0 .. 49151  (48*16*64)
  int l = idx & 63;
  int rest = idx >> 6;
  int ks = rest & 15;
  int nt = rest >> 4;                              // 0..47
  int sel = nt >> 4;
  const float* W = (sel == 0) ? Wg : ((sel == 1) ? Wk : Wr);
  int n = ((nt & 15) * 16) + (l & 15);             // 0..255
  const float* p = W + (size_t)n * 512 + ks * 32 + ((l >> 4) * 8);
  unsigned short* o = out + (size_t)idx * 8;
#pragma unroll
  for (int j = 0; j < 8; ++j) o[j] = f2bf(p[j]);
}

template <bool PACKED>
__device__ __forceinline__ short8 ldB(const unsigned short* __restrict__ wpk,
                                      const float* __restrict__ W,
                                      int nt_global, int ks, int l) {
  if constexpr (PACKED) {
    return *(const short8*)(wpk + (((size_t)nt_global * 16 + ks) * 64 + l) * 8);
  } else {
    int n = ((nt_global & 15) * 16) + (l & 15);
    const float* p = W + (size_t)n * 512 + ks * 32 + ((l >> 4) * 8);
    f32x4 v0 = *(const f32x4*)p;
    f32x4 v1 = *(const f32x4*)(p + 4);
    BF8 r;
#pragma unroll
    for (int j = 0; j < 4; ++j) { r.u[j] = f2bf(v0[j]); r.u[4 + j] = f2bf(v1[j]); }
    return r.s;
  }
}

template <bool PACKED>
__global__ __launch_bounds__(512, 1) void fused_kernel(
    const float* __restrict__ q, const float* __restrict__ qa,
    const float* __restrict__ expw,
    const float* __restrict__ Wg, const float* __restrict__ bg,
    const float* __restrict__ Wk, const float* __restrict__ bk,
    const float* __restrict__ Wr, const float* __restrict__ br,
    const unsigned short* __restrict__ wpk,
    float* __restrict__ out) {
  __shared__ char smem[2 * QT_BYTES];              // 102400 B
  const int b = blockIdx.x;
  const int tid = threadIdx.x;
  const int w = tid >> 6;                          // wave 0..7 (uniform per wave)
  const int l = tid & 63;
  const int lrow = l & 15;
  const int lgrp = l >> 4;

  const float* xqa = qa + (size_t)b * 25600;       // x[:, 0:256)
  const float* xq  = q  + (size_t)b * 25600;       // x[:, 256:512)

  // Async DMA of one k-quarter (qq) into LDS buffer bufi.
  // 50 windows of 1024 B (2 rows); wave w handles windows w, w+8, ...
  // Lane l writes LDS linear chunk l*16 in its window; the SOURCE address is
  // pre-swizzled so LDS row r, slot s holds global k16 = (s - 9*r) & 31.
#define DMA_STAGE(qq, bufi)                                                   \
  {                                                                           \
    const float* srcb = ((qq) < 2 ? xqa : xq) + ((qq) & 1) * 128;             \
    for (int w2 = w; w2 < 50; w2 += 8) {                                      \
      int r   = 2 * w2 + (l >> 5);                                            \
      int sl  = l & 31;                                                       \
      int k16 = (sl - 9 * r) & 31;                                            \
      const float* src = srcb + r * 256 + k16 * 4;                            \
      char* dst = smem + (bufi) * QT_BYTES + w2 * 1024;                       \
      __builtin_amdgcn_global_load_lds(                                       \
          (const __attribute__((address_space(1))) unsigned int*)src,         \
          (__attribute__((address_space(3))) unsigned int*)dst, 16, 0, 0);    \
    }                                                                         \
  }

  DMA_STAGE(0, 0);
  DMA_STAGE(1, 1);
  __syncthreads();                                 // vmcnt(0) drain: q0,q1 resident

  f32x4 accG[7][2], accK[7][2], accR[7][2];
#pragma unroll
  for (int mt = 0; mt < 7; ++mt)
#pragma unroll
    for (int j = 0; j < 2; ++j) {
      accG[mt][j] = (f32x4){0.f, 0.f, 0.f, 0.f};
      accK[mt][j] = (f32x4){0.f, 0.f, 0.f, 0.f};
      accR[mt][j] = (f32x4){0.f, 0.f, 0.f, 0.f};
    }

  int rowOff[7], r9[7];
#pragma unroll
  for (int mt = 0; mt < 7; ++mt) {
    int t = mt * 16 + lrow;
    t = (t > 98) ? 98 : t;                         // clamped lanes broadcast row 98
    rowOff[mt] = t * 512;
    r9[mt] = (9 * t) & 31;
  }

#pragma unroll
  for (int qq = 0; qq < 4; ++qq) {
    // one-ahead prefetch: buffer (qq+1)&1 was last read in iter qq-1
    if (qq == 1) DMA_STAGE(2, 0);
    if (qq == 2) DMA_STAGE(3, 1);
    const char* base = smem + (qq & 1) * QT_BYTES;
#pragma unroll
    for (int kk = 0; kk < 4; ++kk) {
      const int ks = qq * 4 + kk;
      BF8 aF[7];
#pragma unroll
      for (int mt = 0; mt < 7; ++mt) {
        int s0 = (kk * 8 + lgrp * 2 + r9[mt]) & 31;
        int s1 = (s0 + 1) & 31;
        f32x4 v0 = *(const f32x4*)(base + rowOff[mt] + s0 * 16);
        f32x4 v1 = *(const f32x4*)(base + rowOff[mt] + s1 * 16);
        aF[mt].w4[0] = pk2bf(v0[0], v0[1]);
        aF[mt].w4[1] = pk2bf(v0[2], v0[3]);
        aF[mt].w4[2] = pk2bf(v1[0], v1[1]);
        aF[mt].w4[3] = pk2bf(v1[2], v1[3]);
      }
#pragma unroll
      for (int j = 0; j < 2; ++j) {
        short8 bG = ldB<PACKED>(wpk, Wg, w * 2 + j, ks, l);
#pragma unroll
        for (int mt = 0; mt < 7; ++mt)
          accG[mt][j] = __builtin_amdgcn_mfma_f32_16x16x32_bf16(aF[mt].s, bG, accG[mt][j], 0, 0, 0);
        short8 bK = ldB<PACKED>(wpk, Wk, 16 + w * 2 + j, ks, l);
#pragma unroll
        for (int mt = 0; mt < 7; ++mt)
          accK[mt][j] = __builtin_amdgcn_mfma_f32_16x16x32_bf16(aF[mt].s, bK, accK[mt][j], 0, 0, 0);
        short8 bR = ldB<PACKED>(wpk, Wr, 32 + w * 2 + j, ks, l);
#pragma unroll
        for (int mt = 0; mt < 7; ++mt)
          accR[mt][j] = __builtin_amdgcn_mfma_f32_16x16x32_bf16(aF[mt].s, bR, accR[mt][j], 0, 0, 0);
      }
    }
    if (qq < 3) __syncthreads();                   // drains this iter's DMA; buffer handoff
  }

  // ---- epilogue: activations + in-register affine scan + direct stores ----
  // acc layout per (mt,j): lane (lrow,lgrp) holds t = mt*16 + lgrp*4 + r,
  // d = w*32 + j*16 + lrow. Step map: h' = rr*h + cc, cc = (1-rr)*gate*kq.
  float* ob = out + (size_t)b * 25600;
#pragma unroll
  for (int j = 0; j < 2; ++j) {
    const int d = w * 32 + j * 16 + lrow;
    const float bgv = bg[d], bkv = bk[d], brv = br[d];
    float h = expw[d];
    if (lgrp == 0) ob[d] = h;                      // out[b,0,:] = exp
#pragma unroll
    for (int mt = 0; mt < 7; ++mt) {
      float rr[4], cc[4];
#pragma unroll
      for (int r = 0; r < 4; ++r) {
        const int t = mt * 16 + lgrp * 4 + r;
        if (t < 99) {
          float rv = sigm(accR[mt][j][r] + brv);
          float gv = sigm(accG[mt][j][r] + bgv);
          float kv = tanh_(accK[mt][j][r] + bkv);
          rr[r] = rv;
          cc[r] = (1.f - rv) * (gv * kv);
        } else { rr[r] = 1.f; cc[r] = 0.f; }       // identity step for padding
      }
      // compose this lane's 4 steps: h -> A*h + B
      const float A  = ((rr[0] * rr[1]) * rr[2]) * rr[3];
      const float Bc = ((cc[0] * rr[1] + cc[1]) * rr[2] + cc[2]) * rr[3] + cc[3];
      // shuffle scan across the 4 lgrp groups (same lrow column)
      float hcur = h, hstart = h;
#pragma unroll
      for (int g = 0; g < 4; ++g) {
        float ag  = __shfl(A,  lrow + (g << 4), 64);
        float bg_ = __shfl(Bc, lrow + (g << 4), 64);
        hstart = (lgrp == g) ? hcur : hstart;      // exclusive prefix for own group
        hcur = __builtin_fmaf(ag, hcur, bg_);
      }
      h = hcur;                                    // carry to next m-tile
      // reconstruct the 4 per-step h values and store
      float hh = hstart;
#pragma unroll
      for (int r = 0; r < 4; ++r) {
        const int t = mt * 16 + lgrp * 4 + r;
        hh = __builtin_fmaf(rr[r], hh, cc[r]);
        if (t < 99) ob[(t + 1) * 256 + d] = hh;
      }
    }
  }
#undef DMA_STAGE
}

extern "C" void kernel_launch(void* const* d_in, const int* in_sizes, int n_in,
                              void* d_out, int out_size, void* d_ws, size_t ws_size,
                              hipStream_t stream) {
  const float* q    = (const float*)d_in[0];
  const float* qa   = (const float*)d_in[1];
  const float* expw = (const float*)d_in[2];
  const float* Wg   = (const float*)d_in[3];
  const float* bg   = (const float*)d_in[4];
  const float* Wk   = (const float*)d_in[5];
  const float* bk   = (const float*)d_in[6];
  const float* Wr   = (const float*)d_in[7];
  const float* br   = (const float*)d_in[8];
  float* out = (float*)d_out;

  const bool packed = ws_size >= (size_t)(48 * 16 * 64 * 8 * 2);

  if (packed) {
    unsigned short* wpk = (unsigned short*)d_ws;
    pack_w<<<192, 256, 0, stream>>>(Wg, Wk, Wr, wpk);
    fused_kernel<true><<<4096, 512, 0, stream>>>(q, qa, expw, Wg, bg, Wk, bk, Wr, br, wpk, out);
  } else {
    fused_kernel<false><<<4096, 512, 0, stream>>>(q, qa, expw, Wg, bg, Wk, bk, Wr, br, nullptr, out);
  }
}

// Round 6
// 811.563 us; speedup vs baseline: 3.9339x; 1.5461x over previous
//
#include <hip/hip_runtime.h>
#include <hip/hip_bf16.h>

// B=4096, L=100 (SEQLEN=99), d=256, K=2d=512.
// x[b,t,:] = [qa[b,t,:], q[b,t,:]]  (t=0..98)
// gate=sigmoid(x@Wg^T+bg), kq=tanh(x@Wk^T+bk), reset=sigmoid(x@Wr^T+br)
// h_0 = exp; h_{t+1} = r_t*h_t + (1-r_t)*(gate_t*kq_t); out[b] = [exp, h_1..h_99]
//
// Round-6 structure: TWO blocks per b (grid 8192), each handles a 128-col
// d-half for all 99 t. 512 threads (8 waves); wave w owns ONE 16-col n-tile:
// d in [dhalf*128 + w*16, +16).
//  - WHY: rounds 3-5 all spilled ~2 GB of scratch because 168 accumulator
//    f32/thread + staging/fragment regs exceeded the 256-reg/thread cap
//    (8 waves/block = 2 waves/SIMD). Halving the n-tile per wave cuts accs
//    to 84 -> total live ~160, comfortably below the cap. Spill is the
//    dominant cost; everything else is retained from round 5.
//  - block->(b,dhalf) decode pairs g and g+8 as the two halves of one b:
//    same XCD under round-robin dispatch -> the second x-read hits that
//    XCD's L2 (16 b-rows x 203 KB = 3.3 MB < 4 MB per XCD).
//  - x staged as RAW F32 via __builtin_amdgcn_global_load_lds (zero register
//    cost), double-buffered k-quarters (2 x 51200 B LDS), source-address
//    swizzle slot = (k16 + 9*row) & 31 -> <=2-way LDS read conflicts.
//  - f32->bf16 at fragment read (cvt_pk), once per element per block.
//  - recurrence fully in-register (affine-map compose + shuffle scan).

typedef __attribute__((ext_vector_type(4))) float f32x4;
typedef __attribute__((ext_vector_type(8))) short short8;

union BF8 { short8 s; unsigned short u[8]; unsigned int w4[4]; };

static constexpr int QROWS    = 100;             // 99 used + 1 pad row
static constexpr int QT_BYTES = QROWS * 512;     // one f32 k-quarter, 51200 B

__device__ __forceinline__ unsigned short f2bf(float f) {
  unsigned int u = __float_as_uint(f);
  return (unsigned short)((u + 0x7fffu + ((u >> 16) & 1u)) >> 16);   // RNE
}

__device__ __forceinline__ unsigned int pk2bf(float lo, float hi) {
  __hip_bfloat162 h = __float22bfloat162_rn(make_float2(lo, hi));    // v_cvt_pk_bf16_f32
  union { __hip_bfloat162 h2; unsigned int u; } cv;
  cv.h2 = h;
  return cv.u;
}

__device__ __forceinline__ float sigm(float x) { return 1.f / (1.f + __expf(-x)); }
__device__ __forceinline__ float tanh_(float x) {
  x = fminf(fmaxf(x, -15.f), 15.f);
  float e = __expf(2.f * x);
  return (e - 1.f) / (e + 1.f);
}

// Pack Wg|Wk|Wr (each 256x512 f32, row-major) into bf16 B-fragment order:
// [nt(48)][ks(16)][lane(64)][j(8)]; value = W_sel[nt%16*16 + (l&15)][ks*32+(l>>4)*8+j]
__global__ void pack_w(const float* __restrict__ Wg, const float* __restrict__ Wk,
                       const float* __restrict__ Wr, unsigned short* __restrict__ out) {
  int idx = blockIdx.x * 256 + threadIdx.x;        // 0 .. 49151  (48*16*64)
  int l = idx & 63;
  int rest = idx >> 6;
  int ks = rest & 15;
  int nt = rest >> 4;                              // 0..47
  int sel = nt >> 4;
  const float* W = (sel == 0) ? Wg : ((sel == 1) ? Wk : Wr);
  int n = ((nt & 15) * 16) + (l & 15);             // 0..255
  const float* p = W + (size_t)n * 512 + ks * 32 + ((l >> 4) * 8);
  unsigned short* o = out + (size_t)idx * 8;
#pragma unroll
  for (int j = 0; j < 8; ++j) o[j] = f2bf(p[j]);
}

template <bool PACKED>
__device__ __forceinline__ short8 ldB(const unsigned short* __restrict__ wpk,
                                      const float* __restrict__ W,
                                      int nt_global, int ks, int l) {
  if constexpr (PACKED) {
    return *(const short8*)(wpk + (((size_t)nt_global * 16 + ks) * 64 + l) * 8);
  } else {
    int n = ((nt_global & 15) * 16) + (l & 15);
    const float* p = W + (size_t)n * 512 + ks * 32 + ((l >> 4) * 8);
    f32x4 v0 = *(const f32x4*)p;
    f32x4 v1 = *(const f32x4*)(p + 4);
    BF8 r;
#pragma unroll
    for (int j = 0; j < 4; ++j) { r.u[j] = f2bf(v0[j]); r.u[4 + j] = f2bf(v1[j]); }
    return r.s;
  }
}

template <bool PACKED>
__global__ __launch_bounds__(512, 1) void fused_kernel(
    const float* __restrict__ q, const float* __restrict__ qa,
    const float* __restrict__ expw,
    const float* __restrict__ Wg, const float* __restrict__ bg,
    const float* __restrict__ Wk, const float* __restrict__ bk,
    const float* __restrict__ Wr, const float* __restrict__ br,
    const unsigned short* __restrict__ wpk,
    float* __restrict__ out) {
  __shared__ char smem[2 * QT_BYTES];              // 102400 B
  const int g = blockIdx.x;
  const int dhalf = (g >> 3) & 1;                  // pairs (g, g+8): same b, same XCD
  const int b = (g & 7) | ((g >> 4) << 3);         // bijective over 8192
  const int tid = threadIdx.x;
  const int w = tid >> 6;                          // wave 0..7 (uniform per wave)
  const int l = tid & 63;
  const int lrow = l & 15;
  const int lgrp = l >> 4;
  const int ntb = dhalf * 8 + w;                   // this wave's n-tile (0..15)

  const float* xqa = qa + (size_t)b * 25600;       // x[:, 0:256)
  const float* xq  = q  + (size_t)b * 25600;       // x[:, 256:512)

  // Async DMA of one k-quarter (qq) into LDS buffer bufi.
  // 50 windows of 1024 B (2 rows); wave w handles windows w, w+8, ...
  // Lane l writes LDS linear chunk l*16 in its window; the SOURCE address is
  // pre-swizzled so LDS row r, slot s holds global k16 = (s - 9*r) & 31.
#define DMA_STAGE(qq, bufi)                                                   \
  {                                                                           \
    const float* srcb = ((qq) < 2 ? xqa : xq) + ((qq) & 1) * 128;             \
    for (int w2 = w; w2 < 50; w2 += 8) {                                      \
      int r   = 2 * w2 + (l >> 5);                                            \
      int sl  = l & 31;                                                       \
      int k16 = (sl - 9 * r) & 31;                                            \
      const float* src = srcb + r * 256 + k16 * 4;                            \
      char* dst = smem + (bufi) * QT_BYTES + w2 * 1024;                       \
      __builtin_amdgcn_global_load_lds(                                       \
          (const __attribute__((address_space(1))) unsigned int*)src,         \
          (__attribute__((address_space(3))) unsigned int*)dst, 16, 0, 0);    \
    }                                                                         \
  }

  DMA_STAGE(0, 0);
  DMA_STAGE(1, 1);
  __syncthreads();                                 // vmcnt(0) drain: q0,q1 resident

  f32x4 accG[7], accK[7], accR[7];                 // 84 f32/thread total
#pragma unroll
  for (int mt = 0; mt < 7; ++mt) {
    accG[mt] = (f32x4){0.f, 0.f, 0.f, 0.f};
    accK[mt] = (f32x4){0.f, 0.f, 0.f, 0.f};
    accR[mt] = (f32x4){0.f, 0.f, 0.f, 0.f};
  }

  int rowOff[7], r9[7];
#pragma unroll
  for (int mt = 0; mt < 7; ++mt) {
    int t = mt * 16 + lrow;
    t = (t > 98) ? 98 : t;                         // clamped lanes broadcast row 98
    rowOff[mt] = t * 512;
    r9[mt] = (9 * t) & 31;
  }

#pragma unroll
  for (int qq = 0; qq < 4; ++qq) {
    // one-ahead prefetch: buffer (qq+1)&1 was last read in iter qq-1
    if (qq == 1) DMA_STAGE(2, 0);
    if (qq == 2) DMA_STAGE(3, 1);
    const char* base = smem + (qq & 1) * QT_BYTES;
#pragma unroll
    for (int kk = 0; kk < 4; ++kk) {
      const int ks = qq * 4 + kk;
      BF8 aF[7];
#pragma unroll
      for (int mt = 0; mt < 7; ++mt) {
        int s0 = (kk * 8 + lgrp * 2 + r9[mt]) & 31;
        int s1 = (s0 + 1) & 31;
        f32x4 v0 = *(const f32x4*)(base + rowOff[mt] + s0 * 16);
        f32x4 v1 = *(const f32x4*)(base + rowOff[mt] + s1 * 16);
        aF[mt].w4[0] = pk2bf(v0[0], v0[1]);
        aF[mt].w4[1] = pk2bf(v0[2], v0[3]);
        aF[mt].w4[2] = pk2bf(v1[0], v1[1]);
        aF[mt].w4[3] = pk2bf(v1[2], v1[3]);
      }
      short8 bG = ldB<PACKED>(wpk, Wg, ntb, ks, l);
#pragma unroll
      for (int mt = 0; mt < 7; ++mt)
        accG[mt] = __builtin_amdgcn_mfma_f32_16x16x32_bf16(aF[mt].s, bG, accG[mt], 0, 0, 0);
      short8 bK = ldB<PACKED>(wpk, Wk, 16 + ntb, ks, l);
#pragma unroll
      for (int mt = 0; mt < 7; ++mt)
        accK[mt] = __builtin_amdgcn_mfma_f32_16x16x32_bf16(aF[mt].s, bK, accK[mt], 0, 0, 0);
      short8 bR = ldB<PACKED>(wpk, Wr, 32 + ntb, ks, l);
#pragma unroll
      for (int mt = 0; mt < 7; ++mt)
        accR[mt] = __builtin_amdgcn_mfma_f32_16x16x32_bf16(aF[mt].s, bR, accR[mt], 0, 0, 0);
    }
    if (qq < 3) __syncthreads();                   // drains this iter's DMA; buffer handoff
  }

  // ---- epilogue: activations + in-register affine scan + direct stores ----
  // acc layout per mt: lane (lrow,lgrp) holds t = mt*16 + lgrp*4 + r,
  // d = dhalf*128 + w*16 + lrow. Step map: h' = rr*h + cc, cc = (1-rr)*gate*kq.
  float* ob = out + (size_t)b * 25600;
  {
    const int d = dhalf * 128 + w * 16 + lrow;
    const float bgv = bg[d], bkv = bk[d], brv = br[d];
    float h = expw[d];
    if (lgrp == 0) ob[d] = h;                      // out[b,0,:] = exp
#pragma unroll
    for (int mt = 0; mt < 7; ++mt) {
      float rr[4], cc[4];
#pragma unroll
      for (int r = 0; r < 4; ++r) {
        const int t = mt * 16 + lgrp * 4 + r;
        if (t < 99) {
          float rv = sigm(accR[mt][r] + brv);
          float gv = sigm(accG[mt][r] + bgv);
          float kv = tanh_(accK[mt][r] + bkv);
          rr[r] = rv;
          cc[r] = (1.f - rv) * (gv * kv);
        } else { rr[r] = 1.f; cc[r] = 0.f; }       // identity step for padding
      }
      // compose this lane's 4 steps: h -> A*h + B
      const float A  = ((rr[0] * rr[1]) * rr[2]) * rr[3];
      const float Bc = ((cc[0] * rr[1] + cc[1]) * rr[2] + cc[2]) * rr[3] + cc[3];
      // shuffle scan across the 4 lgrp groups (same lrow column)
      float hcur = h, hstart = h;
#pragma unroll
      for (int gg = 0; gg < 4; ++gg) {
        float ag  = __shfl(A,  lrow + (gg << 4), 64);
        float bg_ = __shfl(Bc, lrow + (gg << 4), 64);
        hstart = (lgrp == gg) ? hcur : hstart;     // exclusive prefix for own group
        hcur = __builtin_fmaf(ag, hcur, bg_);
      }
      h = hcur;                                    // carry to next m-tile
      // reconstruct the 4 per-step h values and store
      float hh = hstart;
#pragma unroll
      for (int r = 0; r < 4; ++r) {
        const int t = mt * 16 + lgrp * 4 + r;
        hh = __builtin_fmaf(rr[r], hh, cc[r]);
        if (t < 99) ob[(t + 1) * 256 + d] = hh;
      }
    }
  }
#undef DMA_STAGE
}

extern "C" void kernel_launch(void* const* d_in, const int* in_sizes, int n_in,
                              void* d_out, int out_size, void* d_ws, size_t ws_size,
                              hipStream_t stream) {
  const float* q    = (const float*)d_in[0];
  const float* qa   = (const float*)d_in[1];
  const float* expw = (const float*)d_in[2];
  const float* Wg   = (const float*)d_in[3];
  const float* bg   = (const float*)d_in[4];
  const float* Wk   = (const float*)d_in[5];
  const float* bk   = (const float*)d_in[6];
  const float* Wr   = (const float*)d_in[7];
  const float* br   = (const float*)d_in[8];
  float* out = (float*)d_out;

  const bool packed = ws_size >= (size_t)(48 * 16 * 64 * 8 * 2);

  if (packed) {
    unsigned short* wpk = (unsigned short*)d_ws;
    pack_w<<<192, 256, 0, stream>>>(Wg, Wk, Wr, wpk);
    fused_kernel<true><<<8192, 512, 0, stream>>>(q, qa, expw, Wg, bg, Wk, bk, Wr, br, wpk, out);
  } else {
    fused_kernel<false><<<8192, 512, 0, stream>>>(q, qa, expw, Wg, bg, Wk, bk, Wr, br, nullptr, out);
  }
}